// Round 8
// baseline (457.740 us; speedup 1.0000x reference)
//
#include <hip/hip_runtime.h>
#include <math.h>

// AttnSum3d via bf16-split MFMA + symmetry + bound-shifted softmax.
//   X = x*mask scaled by sqrt(log2 e); Y = [bf16_hi|bf16_lo] (L x 256 bf16).
//   S' = Y Y^T = S*log2(e) (symmetric). Cauchy-Schwarz bound C_m = n_m*Nmax
//   >= column max (overshoot <= Nmax^2/4 ~ 68 log2-units, safe in f32).
//   csum[m] = sum_l exp2(S'[l,m]-C_m);  Q_m = -C_m - log2(csum_m);
//   r[l] = sum_m exp2(S'[l,m]+Q_m);  out[b,0,d] = (1/L) sum_l X[l,d] r[l];
//   attn_mean = 1/L exactly.
// R8: R5's proven regime (BK=128, 64KB LDS, launch_bounds(256,2), half-strip
// blocks: row ib owns d=0..7 wrapped, +8 if ib<8; 512 blocks, XCD-swizzled)
// + R7's verified cheap pure-sum epilogues. R7's (256,4) reg-cap caused a
// spill catastrophe (VGPR 64, FETCH+WRITE ~195MB/dispatch) -- reverted.

constexpr int NB = 16, NL = 2048, ND = 128;
constexpr int ROWS_US = 256;  // ushorts per Y row (K_eff = 256 bf16)
constexpr int NSLOT = 10;     // 0,1 own strip halves (row-dir); 2..9 col-dir d=1..8

typedef __attribute__((ext_vector_type(8))) short short8;
typedef __attribute__((ext_vector_type(4))) float f32x4;

#define EXP2(x) __builtin_amdgcn_exp2f(x)

__device__ __forceinline__ unsigned short f2bf(float f) {
  unsigned u = __builtin_bit_cast(unsigned, f);
  u += 0x7FFFu + ((u >> 16) & 1u);
  return (unsigned short)(u >> 16);
}
__device__ __forceinline__ float bf2f(unsigned short h) {
  unsigned u = ((unsigned)h) << 16;
  return __builtin_bit_cast(float, u);
}

__device__ __forceinline__ void stage16(const unsigned short* g, unsigned short* l) {
  __builtin_amdgcn_global_load_lds(
      (const __attribute__((address_space(1))) unsigned int*)g,
      (__attribute__((address_space(3))) unsigned int*)l, 16, 0, 0);
}

// prep: scale by sqrt(log2 e)*mask, bf16-split, swizzled store, row norm^2,
// per-batch max norm^2 via uint atomicMax (positive floats order-preserving;
// nmax zeroed by hipMemsetAsync before launch).
__global__ __launch_bounds__(256) void k_prep(const float* __restrict__ x,
                                              const float* __restrict__ mask,
                                              unsigned short* __restrict__ Y,
                                              float* __restrict__ nsq,
                                              unsigned int* __restrict__ nmax) {
  const int gid = blockIdx.x * 256 + threadIdx.x;  // one float4 (4 d-elems)
  const int row = gid >> 5;
  const int dq = gid & 31;
  const float4 v = reinterpret_cast<const float4*>(x)[gid];
  const float m = mask[row] * 1.2011224087864498f;  // sqrt(log2 e)
  const float f0 = v.x * m, f1 = v.y * m, f2 = v.z * m, f3 = v.w * m;
  const unsigned short h0 = f2bf(f0), h1 = f2bf(f1), h2 = f2bf(f2), h3 = f2bf(f3);
  const unsigned short e0 = f2bf(f0 - bf2f(h0)), e1 = f2bf(f1 - bf2f(h1)),
                       e2 = f2bf(f2 - bf2f(h2)), e3 = f2bf(f3 - bf2f(h3));
  unsigned short* Yr = Y + (size_t)row * ROWS_US;
  const int sx = dq >> 1, half8 = (dq & 1) * 4;
  const int pos = sx ^ (row & 15);  // XOR within each 16-slot half
  *reinterpret_cast<ushort4*>(Yr + pos * 8 + half8) = make_ushort4(h0, h1, h2, h3);
  *reinterpret_cast<ushort4*>(Yr + (16 + pos) * 8 + half8) = make_ushort4(e0, e1, e2, e3);
  float ss = f0 * f0 + f1 * f1 + f2 * f2 + f3 * f3;
#pragma unroll
  for (int mk = 1; mk < 32; mk <<= 1) ss += __shfl_xor(ss, mk);
  if (dq == 0) {
    nsq[row] = ss;
    atomicMax(nmax + (row >> 11), __builtin_bit_cast(unsigned, ss));
  }
}

// Block decode: xcd = sid&7 owns 2 batches; 32 half-strips per batch.
#define STRIP_DECODE()                                     \
  const int sid = blockIdx.x;                              \
  const int idx = sid >> 3;                                \
  const int b = ((sid & 7) << 1) | (idx >> 5);             \
  const int strip = idx & 31;                              \
  const int ib = strip >> 1, hf = strip & 1;               \
  const int d0 = hf * 4;                                   \
  const int nt = (hf == 0) ? 4 : ((ib < 8) ? 5 : 4);       \
  const int row0 = ib * 128;                               \
  const int tid = threadIdx.x;                             \
  const int lane = tid & 63, wave = tid >> 6;              \
  const int wr = wave >> 1, wc = wave & 1;                 \
  const int lhi = lane >> 4, llo = lane & 15;

// 128x128 tile GEMM, BK=128 x2 chunks (R5's verified body: linear staging so
// LDS inherits Y's per-row XOR swizzle; reads XOR by row&15; 0 bank conflicts).
#define TILE_GEMM(Yb, row0, col0)                                                     \
  f32x4 acc[4][4];                                                                    \
  _Pragma("unroll") for (int rs = 0; rs < 4; ++rs)                                    \
      _Pragma("unroll") for (int cs = 0; cs < 4; ++cs)                                \
          acc[rs][cs] = f32x4{0.f, 0.f, 0.f, 0.f};                                    \
  for (int c = 0; c < 2; ++c) {                                                       \
    __syncthreads();                                                                  \
    _Pragma("unroll") for (int it = 0; it < 8; ++it) {                                \
      const int idx2 = tid + 256 * it;                                                \
      const int r = idx2 >> 4, s = idx2 & 15;                                         \
      stage16(Yb + (size_t)(row0 + r) * ROWS_US + c * 128 + s * 8, At + idx2 * 8);    \
      stage16(Yb + (size_t)(col0 + r) * ROWS_US + c * 128 + s * 8, Bt + idx2 * 8);    \
    }                                                                                 \
    __syncthreads();                                                                  \
    _Pragma("unroll") for (int t4 = 0; t4 < 4; ++t4) {                                \
      const int sl = 4 * t4 + lhi;                                                    \
      short8 af[4], bf[4];                                                            \
      _Pragma("unroll") for (int qq = 0; qq < 4; ++qq) {                              \
        const int ra = 64 * wr + 16 * qq + llo;                                       \
        af[qq] = *(const short8*)(At + ra * 128 + ((sl ^ (ra & 15)) << 3));           \
        const int rb = 64 * wc + 16 * qq + llo;                                       \
        bf[qq] = *(const short8*)(Bt + rb * 128 + ((sl ^ (rb & 15)) << 3));           \
      }                                                                               \
      _Pragma("unroll") for (int rs = 0; rs < 4; ++rs)                                \
          _Pragma("unroll") for (int cs = 0; cs < 4; ++cs)                            \
              acc[rs][cs] = __builtin_amdgcn_mfma_f32_16x16x32_bf16(af[rs], bf[cs],   \
                                                                    acc[rs][cs], 0, 0, 0); \
    }                                                                                 \
  }

// ---- pass 1: csum partials (pure sums, no max tracking) ----
__global__ __launch_bounds__(256, 2) void k_esum(const unsigned short* __restrict__ Y,
                                                 const float* __restrict__ nsq,
                                                 const float* __restrict__ nmaxf,
                                                 float* __restrict__ pcs) {
  __shared__ alignas(128) char lds[65536 + 2048];
  unsigned short* At = (unsigned short*)lds;
  unsigned short* Bt = (unsigned short*)(lds + 32768);
  float* ebuf = (float*)(lds + 65536);  // [2 wr][128] dedicated (1 barrier/epilogue)
  float* rbuf = (float*)(lds + 66560);  // [2 wc][128]
  STRIP_DECODE()
  const unsigned short* Yb = Y + (size_t)b * NL * ROWS_US;
  const float Nmx = nmaxf[b];

  float Cr[16];
#pragma unroll
  for (int rs = 0; rs < 4; ++rs)
#pragma unroll
    for (int rg = 0; rg < 4; ++rg)
      Cr[rs * 4 + rg] = sqrtf(nsq[b * NL + row0 + 64 * wr + 16 * rs + 4 * lhi + rg] * Nmx);

  float racc[16];
#pragma unroll
  for (int i = 0; i < 16; ++i) racc[i] = 0.f;

  for (int dt = 0; dt < nt; ++dt) {
    const int d = d0 + dt;
    const int col0 = ((ib + d) & 15) * 128;
    float Cc[4];
#pragma unroll
    for (int cs = 0; cs < 4; ++cs)
      Cc[cs] = sqrtf(nsq[b * NL + col0 + 64 * wc + 16 * cs + llo] * Nmx);
    TILE_GEMM(Yb, row0, col0)
    // row-direction: csum[row0+i] partial (sum over this tile's cols)
#pragma unroll
    for (int rs = 0; rs < 4; ++rs)
#pragma unroll
      for (int rg = 0; rg < 4; ++rg) {
        float t = 0.f;
#pragma unroll
        for (int cs = 0; cs < 4; ++cs) t += EXP2(acc[rs][cs][rg] - Cr[rs * 4 + rg]);
        racc[rs * 4 + rg] += t;
      }
    // col-direction: csum[col0+j] partial (sum over this tile's rows)
    if (d != 0) {
#pragma unroll
      for (int cs = 0; cs < 4; ++cs) {
        float u = 0.f;
#pragma unroll
        for (int rs = 0; rs < 4; ++rs)
#pragma unroll
          for (int rg = 0; rg < 4; ++rg) u += EXP2(acc[rs][cs][rg] - Cc[cs]);
        u += __shfl_xor(u, 16);
        u += __shfl_xor(u, 32);
        if (lhi == 0) ebuf[wr * 128 + 64 * wc + 16 * cs + llo] = u;
      }
      __syncthreads();
      if (tid < 128)
        pcs[((size_t)(b * NSLOT + 1 + d)) * NL + col0 + tid] = ebuf[tid] + ebuf[128 + tid];
    }
  }
#pragma unroll
  for (int i = 0; i < 16; ++i) {
    float s = racc[i];
#pragma unroll
    for (int mk = 1; mk < 16; mk <<= 1) s += __shfl_xor(s, mk);
    racc[i] = s;
  }
  if (llo == 0) {
#pragma unroll
    for (int rs = 0; rs < 4; ++rs)
#pragma unroll
      for (int rg = 0; rg < 4; ++rg)
        rbuf[wc * 128 + 64 * wr + 16 * rs + 4 * lhi + rg] = racc[rs * 4 + rg];
  }
  __syncthreads();
  if (tid < 128)
    pcs[((size_t)(b * NSLOT + hf)) * NL + row0 + tid] = rbuf[tid] + rbuf[128 + tid];
}

// csum partials -> Q = -C - log2(csum)
__global__ __launch_bounds__(256) void k_comb(const float* __restrict__ pcs,
                                              const float* __restrict__ nsq,
                                              const float* __restrict__ nmaxf,
                                              float* __restrict__ Q) {
  const int i = blockIdx.x * 256 + threadIdx.x;  // b*NL + row
  const int b = i >> 11, row = i & (NL - 1);
  const int o = row >> 7;
  float s = 0.f;
#pragma unroll
  for (int c = 0; c < NSLOT; ++c) {
    if (c == 9 && o < 8) continue;  // slot 9 (d=8) only for owners >= 8
    s += pcs[((size_t)(b * NSLOT + c)) * NL + row];
  }
  Q[i] = -sqrtf(nsq[i] * nmaxf[b]) - __log2f(s);
}

// ---- pass 2: r partials: r[l] = sum_m exp2(S' + Q_m) ----
__global__ __launch_bounds__(256, 2) void k_r(const unsigned short* __restrict__ Y,
                                              const float* __restrict__ Qa,
                                              float* __restrict__ rp) {
  __shared__ alignas(128) char lds[65536 + 2048];
  unsigned short* At = (unsigned short*)lds;
  unsigned short* Bt = (unsigned short*)(lds + 32768);
  float* ebuf = (float*)(lds + 65536);
  float* rbuf = (float*)(lds + 66560);
  STRIP_DECODE()
  const unsigned short* Yb = Y + (size_t)b * NL * ROWS_US;

  float Qr[16];
#pragma unroll
  for (int rs = 0; rs < 4; ++rs)
#pragma unroll
    for (int rg = 0; rg < 4; ++rg)
      Qr[rs * 4 + rg] = Qa[b * NL + row0 + 64 * wr + 16 * rs + 4 * lhi + rg];

  float racc[16];
#pragma unroll
  for (int i = 0; i < 16; ++i) racc[i] = 0.f;

  for (int dt = 0; dt < nt; ++dt) {
    const int d = d0 + dt;
    const int col0 = ((ib + d) & 15) * 128;
    float Qc[4];
#pragma unroll
    for (int cs = 0; cs < 4; ++cs) Qc[cs] = Qa[b * NL + col0 + 64 * wc + 16 * cs + llo];
    TILE_GEMM(Yb, row0, col0)
    // row-direction: r[row0+i] += sum_m exp2(S' + Q_m) over tile cols
#pragma unroll
    for (int rs = 0; rs < 4; ++rs)
#pragma unroll
      for (int rg = 0; rg < 4; ++rg) {
        float t = 0.f;
#pragma unroll
        for (int cs = 0; cs < 4; ++cs) t += EXP2(acc[rs][cs][rg] + Qc[cs]);
        racc[rs * 4 + rg] += t;
      }
    // col-direction: r[col0+j] += sum over tile rows
    if (d != 0) {
#pragma unroll
      for (int cs = 0; cs < 4; ++cs) {
        float u = 0.f;
#pragma unroll
        for (int rs = 0; rs < 4; ++rs)
#pragma unroll
          for (int rg = 0; rg < 4; ++rg) u += EXP2(acc[rs][cs][rg] + Qr[rs * 4 + rg]);
        u += __shfl_xor(u, 16);
        u += __shfl_xor(u, 32);
        if (lhi == 0) ebuf[wr * 128 + 64 * wc + 16 * cs + llo] = u;
      }
      __syncthreads();
      if (tid < 128)
        rp[((size_t)(b * NSLOT + 1 + d)) * NL + col0 + tid] = ebuf[tid] + ebuf[128 + tid];
    }
  }
#pragma unroll
  for (int i = 0; i < 16; ++i) {
    float s = racc[i];
#pragma unroll
    for (int mk = 1; mk < 16; mk <<= 1) s += __shfl_xor(s, mk);
    racc[i] = s;
  }
  if (llo == 0) {
#pragma unroll
    for (int rs = 0; rs < 4; ++rs)
#pragma unroll
      for (int rg = 0; rg < 4; ++rg)
        rbuf[wc * 128 + 64 * wr + 16 * rs + 4 * lhi + rg] = racc[rs * 4 + rg];
  }
  __syncthreads();
  if (tid < 128)
    rp[((size_t)(b * NSLOT + hf)) * NL + row0 + tid] = rbuf[tid] + rbuf[128 + tid];
}

// ---- pass 3a: per-(b,seg) partial of sum_l w[l]*x[l,:] ----
__global__ __launch_bounds__(256) void k_outp(const float* __restrict__ x,
                                              const float* __restrict__ mask,
                                              const float* __restrict__ rp,
                                              float* __restrict__ partial) {
  const int b = blockIdx.y;
  const int seg = blockIdx.x;  // 16 segments of 128 rows; owner block == seg
  const int tid = threadIdx.x;
  const int l0 = seg * 128;
  __shared__ float w_s[128];
  __shared__ float4 red[8][32];
  if (tid < 128) {
    float s = 0.f;
#pragma unroll
    for (int c = 0; c < NSLOT; ++c) {
      if (c == 9 && seg < 8) continue;
      s += rp[((size_t)(b * NSLOT + c)) * NL + l0 + tid];
    }
    w_s[tid] = s * mask[b * NL + l0 + tid];
  }
  __syncthreads();
  const int dq = tid & 31;
  const int rg = tid >> 5;
  float4 acc = make_float4(0.f, 0.f, 0.f, 0.f);
#pragma unroll 4
  for (int i = 0; i < 16; ++i) {
    const int l = 8 * i + rg;
    const float w = w_s[l];
    const float4 v = *reinterpret_cast<const float4*>(x + ((size_t)b * NL + l0 + l) * ND + 4 * dq);
    acc.x += w * v.x; acc.y += w * v.y; acc.z += w * v.z; acc.w += w * v.w;
  }
  red[rg][dq] = acc;
  __syncthreads();
  if (rg == 0) {
    float4 s = acc;
#pragma unroll
    for (int k = 1; k < 8; ++k) {
      const float4 t = red[k][dq];
      s.x += t.x; s.y += t.y; s.z += t.z; s.w += t.w;
    }
    *reinterpret_cast<float4*>(partial + ((size_t)(b * 16 + seg)) * ND + 4 * dq) = s;
  }
}

// ---- pass 3b: finalize out + constant attn_mean fill ----
__global__ __launch_bounds__(1024) void k_fin(const float* __restrict__ partial,
                                              float* __restrict__ out) {
  const int gid = blockIdx.x * 1024 + threadIdx.x;  // 0..32767
  if (gid < NB * ND) {
    const int b = gid >> 7, d = gid & (ND - 1);
    float s = 0.f;
#pragma unroll
    for (int k = 0; k < 16; ++k) s += partial[(size_t)(b * 16 + k) * ND + d];
    out[gid] = s * (1.0f / NL);
  }
  out[NB * ND + gid] = 1.0f / NL;  // attn_mean == 1/L exactly
}

extern "C" void kernel_launch(void* const* d_in, const int* in_sizes, int n_in,
                              void* d_out, int out_size, void* d_ws, size_t ws_size,
                              hipStream_t stream) {
  const float* x = (const float*)d_in[0];     // [16,2048,128] f32
  const float* mask = (const float*)d_in[1];  // [16,2048] f32
  float* out = (float*)d_out;

  unsigned short* Y = (unsigned short*)d_ws;                   // 16.8 MB
  float* nsq = (float*)(Y + (size_t)NB * NL * ROWS_US);        // [NB*NL]
  float* nmaxf = nsq + NB * NL;                                // [NB]
  float* pcs = nmaxf + 16;                                     // [NB*NSLOT*NL]
  float* rp = pcs;                                             // alias (pcs consumed first)
  float* Q = pcs + (size_t)NB * NSLOT * NL;                    // [NB*NL]
  float* partial = Q + NB * NL;                                // [NB*16*ND]

  hipMemsetAsync(nmaxf, 0, NB * sizeof(float), stream);
  k_prep<<<dim3(NB * NL * ND / 4 / 256), 256, 0, stream>>>(x, mask, Y, nsq,
                                                           (unsigned int*)nmaxf);
  k_esum<<<dim3(512), 256, 0, stream>>>(Y, nsq, nmaxf, pcs);
  k_comb<<<dim3(NB * NL / 256), 256, 0, stream>>>(pcs, nsq, nmaxf, Q);
  k_r<<<dim3(512), 256, 0, stream>>>(Y, Q, rp);
  k_outp<<<dim3(16, NB), 256, 0, stream>>>(x, mask, rp, partial);
  k_fin<<<32, 1024, 0, stream>>>(partial, out);
}

// Round 9
// 87.997 us; speedup vs baseline: 5.2018x; 5.2018x over previous
//
#include <hip/hip_runtime.h>
#include <math.h>

// AttnSum3d via bf16-split MFMA + symmetry + bound-shifted softmax.
//   X = x*mask scaled by sqrt(log2 e); Y = [bf16_hi|bf16_lo] (L x 256 bf16).
//   S' = Y Y^T = S*log2(e) (symmetric). Cauchy-Schwarz bound C_m = n_m*Nmax
//   >= column max (overshoot <= Nmax^2/4 ~ 68 log2-units, safe in f32).
//   csum[m] = sum_l exp2(S'[l,m]-C_m);  Q_m = -C_m - log2(csum_m);
//   r[l] = sum_m exp2(S'[l,m]+Q_m);  out[b,0,d] = (1/L) sum_l X[l,d] r[l];
//   attn_mean = 1/L exactly.
// R9: R8 minus the atomicMax-in-k_prep regression (8192 device-scope atomics
// to ONE cache line = 375us serialized; Guideline 12). Dedicated 16-block
// k_nmax reduction kernel restored (R7-style, ~2us).

constexpr int NB = 16, NL = 2048, ND = 128;
constexpr int ROWS_US = 256;  // ushorts per Y row (K_eff = 256 bf16)
constexpr int NSLOT = 10;     // 0,1 own strip halves (row-dir); 2..9 col-dir d=1..8

typedef __attribute__((ext_vector_type(8))) short short8;
typedef __attribute__((ext_vector_type(4))) float f32x4;

#define EXP2(x) __builtin_amdgcn_exp2f(x)

__device__ __forceinline__ unsigned short f2bf(float f) {
  unsigned u = __builtin_bit_cast(unsigned, f);
  u += 0x7FFFu + ((u >> 16) & 1u);
  return (unsigned short)(u >> 16);
}
__device__ __forceinline__ float bf2f(unsigned short h) {
  unsigned u = ((unsigned)h) << 16;
  return __builtin_bit_cast(float, u);
}

__device__ __forceinline__ void stage16(const unsigned short* g, unsigned short* l) {
  __builtin_amdgcn_global_load_lds(
      (const __attribute__((address_space(1))) unsigned int*)g,
      (__attribute__((address_space(3))) unsigned int*)l, 16, 0, 0);
}

// prep: scale by sqrt(log2 e)*mask, bf16-split, swizzled store, row norm^2.
__global__ __launch_bounds__(256) void k_prep(const float* __restrict__ x,
                                              const float* __restrict__ mask,
                                              unsigned short* __restrict__ Y,
                                              float* __restrict__ nsq) {
  const int gid = blockIdx.x * 256 + threadIdx.x;  // one float4 (4 d-elems)
  const int row = gid >> 5;
  const int dq = gid & 31;
  const float4 v = reinterpret_cast<const float4*>(x)[gid];
  const float m = mask[row] * 1.2011224087864498f;  // sqrt(log2 e)
  const float f0 = v.x * m, f1 = v.y * m, f2 = v.z * m, f3 = v.w * m;
  const unsigned short h0 = f2bf(f0), h1 = f2bf(f1), h2 = f2bf(f2), h3 = f2bf(f3);
  const unsigned short e0 = f2bf(f0 - bf2f(h0)), e1 = f2bf(f1 - bf2f(h1)),
                       e2 = f2bf(f2 - bf2f(h2)), e3 = f2bf(f3 - bf2f(h3));
  unsigned short* Yr = Y + (size_t)row * ROWS_US;
  const int sx = dq >> 1, half8 = (dq & 1) * 4;
  const int pos = sx ^ (row & 15);  // XOR within each 16-slot half
  *reinterpret_cast<ushort4*>(Yr + pos * 8 + half8) = make_ushort4(h0, h1, h2, h3);
  *reinterpret_cast<ushort4*>(Yr + (16 + pos) * 8 + half8) = make_ushort4(e0, e1, e2, e3);
  float ss = f0 * f0 + f1 * f1 + f2 * f2 + f3 * f3;
#pragma unroll
  for (int mk = 1; mk < 32; mk <<= 1) ss += __shfl_xor(ss, mk);
  if (dq == 0) nsq[row] = ss;
}

// per-batch max row-norm^2 (16 blocks, ~2us; NOT fused into k_prep -- R8's
// single-cache-line atomicMax serialized to 375us).
__global__ __launch_bounds__(256) void k_nmax(const float* __restrict__ nsq,
                                              float* __restrict__ nmax) {
  const int b = blockIdx.x;
  const int tid = threadIdx.x;
  float m = 0.f;
  for (int i = tid; i < NL; i += 256) m = fmaxf(m, nsq[b * NL + i]);
#pragma unroll
  for (int mk = 1; mk < 64; mk <<= 1) m = fmaxf(m, __shfl_xor(m, mk));
  __shared__ float red[4];
  if ((tid & 63) == 0) red[tid >> 6] = m;
  __syncthreads();
  if (tid == 0) nmax[b] = fmaxf(fmaxf(red[0], red[1]), fmaxf(red[2], red[3]));
}

// Block decode: xcd = sid&7 owns 2 batches; 32 half-strips per batch.
#define STRIP_DECODE()                                     \
  const int sid = blockIdx.x;                              \
  const int idx = sid >> 3;                                \
  const int b = ((sid & 7) << 1) | (idx >> 5);             \
  const int strip = idx & 31;                              \
  const int ib = strip >> 1, hf = strip & 1;               \
  const int d0 = hf * 4;                                   \
  const int nt = (hf == 0) ? 4 : ((ib < 8) ? 5 : 4);       \
  const int row0 = ib * 128;                               \
  const int tid = threadIdx.x;                             \
  const int lane = tid & 63, wave = tid >> 6;              \
  const int wr = wave >> 1, wc = wave & 1;                 \
  const int lhi = lane >> 4, llo = lane & 15;

// 128x128 tile GEMM, BK=128 x2 chunks (R5's verified body: linear staging so
// LDS inherits Y's per-row XOR swizzle; reads XOR by row&15; 0 bank conflicts).
#define TILE_GEMM(Yb, row0, col0)                                                     \
  f32x4 acc[4][4];                                                                    \
  _Pragma("unroll") for (int rs = 0; rs < 4; ++rs)                                    \
      _Pragma("unroll") for (int cs = 0; cs < 4; ++cs)                                \
          acc[rs][cs] = f32x4{0.f, 0.f, 0.f, 0.f};                                    \
  for (int c = 0; c < 2; ++c) {                                                       \
    __syncthreads();                                                                  \
    _Pragma("unroll") for (int it = 0; it < 8; ++it) {                                \
      const int idx2 = tid + 256 * it;                                                \
      const int r = idx2 >> 4, s = idx2 & 15;                                         \
      stage16(Yb + (size_t)(row0 + r) * ROWS_US + c * 128 + s * 8, At + idx2 * 8);    \
      stage16(Yb + (size_t)(col0 + r) * ROWS_US + c * 128 + s * 8, Bt + idx2 * 8);    \
    }                                                                                 \
    __syncthreads();                                                                  \
    _Pragma("unroll") for (int t4 = 0; t4 < 4; ++t4) {                                \
      const int sl = 4 * t4 + lhi;                                                    \
      short8 af[4], bf[4];                                                            \
      _Pragma("unroll") for (int qq = 0; qq < 4; ++qq) {                              \
        const int ra = 64 * wr + 16 * qq + llo;                                       \
        af[qq] = *(const short8*)(At + ra * 128 + ((sl ^ (ra & 15)) << 3));           \
        const int rb = 64 * wc + 16 * qq + llo;                                       \
        bf[qq] = *(const short8*)(Bt + rb * 128 + ((sl ^ (rb & 15)) << 3));           \
      }                                                                               \
      _Pragma("unroll") for (int rs = 0; rs < 4; ++rs)                                \
          _Pragma("unroll") for (int cs = 0; cs < 4; ++cs)                            \
              acc[rs][cs] = __builtin_amdgcn_mfma_f32_16x16x32_bf16(af[rs], bf[cs],   \
                                                                    acc[rs][cs], 0, 0, 0); \
    }                                                                                 \
  }

// ---- pass 1: csum partials (pure sums, no max tracking) ----
__global__ __launch_bounds__(256, 2) void k_esum(const unsigned short* __restrict__ Y,
                                                 const float* __restrict__ nsq,
                                                 const float* __restrict__ nmaxf,
                                                 float* __restrict__ pcs) {
  __shared__ alignas(128) char lds[65536 + 2048];
  unsigned short* At = (unsigned short*)lds;
  unsigned short* Bt = (unsigned short*)(lds + 32768);
  float* ebuf = (float*)(lds + 65536);  // [2 wr][128] dedicated (1 barrier/epilogue)
  float* rbuf = (float*)(lds + 66560);  // [2 wc][128]
  STRIP_DECODE()
  const unsigned short* Yb = Y + (size_t)b * NL * ROWS_US;
  const float Nmx = nmaxf[b];

  float Cr[16];
#pragma unroll
  for (int rs = 0; rs < 4; ++rs)
#pragma unroll
    for (int rg = 0; rg < 4; ++rg)
      Cr[rs * 4 + rg] = sqrtf(nsq[b * NL + row0 + 64 * wr + 16 * rs + 4 * lhi + rg] * Nmx);

  float racc[16];
#pragma unroll
  for (int i = 0; i < 16; ++i) racc[i] = 0.f;

  for (int dt = 0; dt < nt; ++dt) {
    const int d = d0 + dt;
    const int col0 = ((ib + d) & 15) * 128;
    float Cc[4];
#pragma unroll
    for (int cs = 0; cs < 4; ++cs)
      Cc[cs] = sqrtf(nsq[b * NL + col0 + 64 * wc + 16 * cs + llo] * Nmx);
    TILE_GEMM(Yb, row0, col0)
    // row-direction: csum[row0+i] partial (sum over this tile's cols)
#pragma unroll
    for (int rs = 0; rs < 4; ++rs)
#pragma unroll
      for (int rg = 0; rg < 4; ++rg) {
        float t = 0.f;
#pragma unroll
        for (int cs = 0; cs < 4; ++cs) t += EXP2(acc[rs][cs][rg] - Cr[rs * 4 + rg]);
        racc[rs * 4 + rg] += t;
      }
    // col-direction: csum[col0+j] partial (sum over this tile's rows)
    if (d != 0) {
#pragma unroll
      for (int cs = 0; cs < 4; ++cs) {
        float u = 0.f;
#pragma unroll
        for (int rs = 0; rs < 4; ++rs)
#pragma unroll
          for (int rg = 0; rg < 4; ++rg) u += EXP2(acc[rs][cs][rg] - Cc[cs]);
        u += __shfl_xor(u, 16);
        u += __shfl_xor(u, 32);
        if (lhi == 0) ebuf[wr * 128 + 64 * wc + 16 * cs + llo] = u;
      }
      __syncthreads();
      if (tid < 128)
        pcs[((size_t)(b * NSLOT + 1 + d)) * NL + col0 + tid] = ebuf[tid] + ebuf[128 + tid];
    }
  }
#pragma unroll
  for (int i = 0; i < 16; ++i) {
    float s = racc[i];
#pragma unroll
    for (int mk = 1; mk < 16; mk <<= 1) s += __shfl_xor(s, mk);
    racc[i] = s;
  }
  if (llo == 0) {
#pragma unroll
    for (int rs = 0; rs < 4; ++rs)
#pragma unroll
      for (int rg = 0; rg < 4; ++rg)
        rbuf[wc * 128 + 64 * wr + 16 * rs + 4 * lhi + rg] = racc[rs * 4 + rg];
  }
  __syncthreads();
  if (tid < 128)
    pcs[((size_t)(b * NSLOT + hf)) * NL + row0 + tid] = rbuf[tid] + rbuf[128 + tid];
}

// csum partials -> Q = -C - log2(csum)
__global__ __launch_bounds__(256) void k_comb(const float* __restrict__ pcs,
                                              const float* __restrict__ nsq,
                                              const float* __restrict__ nmaxf,
                                              float* __restrict__ Q) {
  const int i = blockIdx.x * 256 + threadIdx.x;  // b*NL + row
  const int b = i >> 11, row = i & (NL - 1);
  const int o = row >> 7;
  float s = 0.f;
#pragma unroll
  for (int c = 0; c < NSLOT; ++c) {
    if (c == 9 && o < 8) continue;  // slot 9 (d=8) only for owners >= 8
    s += pcs[((size_t)(b * NSLOT + c)) * NL + row];
  }
  Q[i] = -sqrtf(nsq[i] * nmaxf[b]) - __log2f(s);
}

// ---- pass 2: r partials: r[l] = sum_m exp2(S' + Q_m) ----
__global__ __launch_bounds__(256, 2) void k_r(const unsigned short* __restrict__ Y,
                                              const float* __restrict__ Qa,
                                              float* __restrict__ rp) {
  __shared__ alignas(128) char lds[65536 + 2048];
  unsigned short* At = (unsigned short*)lds;
  unsigned short* Bt = (unsigned short*)(lds + 32768);
  float* ebuf = (float*)(lds + 65536);
  float* rbuf = (float*)(lds + 66560);
  STRIP_DECODE()
  const unsigned short* Yb = Y + (size_t)b * NL * ROWS_US;

  float Qr[16];
#pragma unroll
  for (int rs = 0; rs < 4; ++rs)
#pragma unroll
    for (int rg = 0; rg < 4; ++rg)
      Qr[rs * 4 + rg] = Qa[b * NL + row0 + 64 * wr + 16 * rs + 4 * lhi + rg];

  float racc[16];
#pragma unroll
  for (int i = 0; i < 16; ++i) racc[i] = 0.f;

  for (int dt = 0; dt < nt; ++dt) {
    const int d = d0 + dt;
    const int col0 = ((ib + d) & 15) * 128;
    float Qc[4];
#pragma unroll
    for (int cs = 0; cs < 4; ++cs) Qc[cs] = Qa[b * NL + col0 + 64 * wc + 16 * cs + llo];
    TILE_GEMM(Yb, row0, col0)
    // row-direction: r[row0+i] += sum_m exp2(S' + Q_m) over tile cols
#pragma unroll
    for (int rs = 0; rs < 4; ++rs)
#pragma unroll
      for (int rg = 0; rg < 4; ++rg) {
        float t = 0.f;
#pragma unroll
        for (int cs = 0; cs < 4; ++cs) t += EXP2(acc[rs][cs][rg] + Qc[cs]);
        racc[rs * 4 + rg] += t;
      }
    // col-direction: r[col0+j] += sum over tile rows
    if (d != 0) {
#pragma unroll
      for (int cs = 0; cs < 4; ++cs) {
        float u = 0.f;
#pragma unroll
        for (int rs = 0; rs < 4; ++rs)
#pragma unroll
          for (int rg = 0; rg < 4; ++rg) u += EXP2(acc[rs][cs][rg] + Qr[rs * 4 + rg]);
        u += __shfl_xor(u, 16);
        u += __shfl_xor(u, 32);
        if (lhi == 0) ebuf[wr * 128 + 64 * wc + 16 * cs + llo] = u;
      }
      __syncthreads();
      if (tid < 128)
        rp[((size_t)(b * NSLOT + 1 + d)) * NL + col0 + tid] = ebuf[tid] + ebuf[128 + tid];
    }
  }
#pragma unroll
  for (int i = 0; i < 16; ++i) {
    float s = racc[i];
#pragma unroll
    for (int mk = 1; mk < 16; mk <<= 1) s += __shfl_xor(s, mk);
    racc[i] = s;
  }
  if (llo == 0) {
#pragma unroll
    for (int rs = 0; rs < 4; ++rs)
#pragma unroll
      for (int rg = 0; rg < 4; ++rg)
        rbuf[wc * 128 + 64 * wr + 16 * rs + 4 * lhi + rg] = racc[rs * 4 + rg];
  }
  __syncthreads();
  if (tid < 128)
    rp[((size_t)(b * NSLOT + hf)) * NL + row0 + tid] = rbuf[tid] + rbuf[128 + tid];
}

// ---- pass 3a: per-(b,seg) partial of sum_l w[l]*x[l,:] ----
__global__ __launch_bounds__(256) void k_outp(const float* __restrict__ x,
                                              const float* __restrict__ mask,
                                              const float* __restrict__ rp,
                                              float* __restrict__ partial) {
  const int b = blockIdx.y;
  const int seg = blockIdx.x;  // 16 segments of 128 rows; owner block == seg
  const int tid = threadIdx.x;
  const int l0 = seg * 128;
  __shared__ float w_s[128];
  __shared__ float4 red[8][32];
  if (tid < 128) {
    float s = 0.f;
#pragma unroll
    for (int c = 0; c < NSLOT; ++c) {
      if (c == 9 && seg < 8) continue;
      s += rp[((size_t)(b * NSLOT + c)) * NL + l0 + tid];
    }
    w_s[tid] = s * mask[b * NL + l0 + tid];
  }
  __syncthreads();
  const int dq = tid & 31;
  const int rg = tid >> 5;
  float4 acc = make_float4(0.f, 0.f, 0.f, 0.f);
#pragma unroll 4
  for (int i = 0; i < 16; ++i) {
    const int l = 8 * i + rg;
    const float w = w_s[l];
    const float4 v = *reinterpret_cast<const float4*>(x + ((size_t)b * NL + l0 + l) * ND + 4 * dq);
    acc.x += w * v.x; acc.y += w * v.y; acc.z += w * v.z; acc.w += w * v.w;
  }
  red[rg][dq] = acc;
  __syncthreads();
  if (rg == 0) {
    float4 s = acc;
#pragma unroll
    for (int k = 1; k < 8; ++k) {
      const float4 t = red[k][dq];
      s.x += t.x; s.y += t.y; s.z += t.z; s.w += t.w;
    }
    *reinterpret_cast<float4*>(partial + ((size_t)(b * 16 + seg)) * ND + 4 * dq) = s;
  }
}

// ---- pass 3b: finalize out + constant attn_mean fill ----
__global__ __launch_bounds__(1024) void k_fin(const float* __restrict__ partial,
                                              float* __restrict__ out) {
  const int gid = blockIdx.x * 1024 + threadIdx.x;  // 0..32767
  if (gid < NB * ND) {
    const int b = gid >> 7, d = gid & (ND - 1);
    float s = 0.f;
#pragma unroll
    for (int k = 0; k < 16; ++k) s += partial[(size_t)(b * 16 + k) * ND + d];
    out[gid] = s * (1.0f / NL);
  }
  out[NB * ND + gid] = 1.0f / NL;  // attn_mean == 1/L exactly
}

extern "C" void kernel_launch(void* const* d_in, const int* in_sizes, int n_in,
                              void* d_out, int out_size, void* d_ws, size_t ws_size,
                              hipStream_t stream) {
  const float* x = (const float*)d_in[0];     // [16,2048,128] f32
  const float* mask = (const float*)d_in[1];  // [16,2048] f32
  float* out = (float*)d_out;

  unsigned short* Y = (unsigned short*)d_ws;                   // 16.8 MB
  float* nsq = (float*)(Y + (size_t)NB * NL * ROWS_US);        // [NB*NL]
  float* nmaxf = nsq + NB * NL;                                // [NB]
  float* pcs = nmaxf + 16;                                     // [NB*NSLOT*NL]
  float* rp = pcs;                                             // alias (pcs consumed first)
  float* Q = pcs + (size_t)NB * NSLOT * NL;                    // [NB*NL]
  float* partial = Q + NB * NL;                                // [NB*16*ND]

  k_prep<<<dim3(NB * NL * ND / 4 / 256), 256, 0, stream>>>(x, mask, Y, nsq);
  k_nmax<<<NB, 256, 0, stream>>>(nsq, nmaxf);
  k_esum<<<dim3(512), 256, 0, stream>>>(Y, nsq, nmaxf, pcs);
  k_comb<<<dim3(NB * NL / 256), 256, 0, stream>>>(pcs, nsq, nmaxf, Q);
  k_r<<<dim3(512), 256, 0, stream>>>(Y, Q, rp);
  k_outp<<<dim3(16, NB), 256, 0, stream>>>(x, mask, rp, partial);
  k_fin<<<32, 1024, 0, stream>>>(partial, out);
}

// Round 10
// 86.909 us; speedup vs baseline: 5.2669x; 1.0125x over previous
//
#include <hip/hip_runtime.h>
#include <math.h>

// AttnSum3d via bf16-split MFMA + symmetry + bound-shifted softmax.
//   X = x*mask scaled by sqrt(log2 e); Y = [bf16_hi|bf16_lo] (L x 256 bf16).
//   S' = Y Y^T = S*log2(e) (symmetric). Cauchy-Schwarz bound C_m = n_m*Nmax
//   >= column max (overshoot <= Nmax^2/4 ~ 68 log2-units, safe in f32).
//   csum[m] = sum_l exp2(S'[l,m]-C_m);  Q_m = -C_m - log2(csum_m);
//   r[l] = sum_m exp2(S'[l,m]+Q_m);  out[b,0,d] = (1/L) sum_l X[l,d] r[l];
//   attn_mean = 1/L exactly.
// R10: barrier-free epilogues. R9's per-tile col-dir partials went
// shuffle -> LDS -> __syncthreads -> tid<128 combine -> store (~5 extra
// barriers/strip, half threads idle); now each WAVE writes its reduced
// partial straight to a distinct global slot (NSLOT 10 -> 20: row-dir
// slot 2*hf+wc with rows disjoint across wr; col-dir slot 4+2*(d-1)+wr
// with cols disjoint across wc). Combine cost moves into the tiny
// k_comb/k_outp kernels. GEMM body/swizzle/decode identical to R9.

constexpr int NB = 16, NL = 2048, ND = 128;
constexpr int ROWS_US = 256;  // ushorts per Y row (K_eff = 256 bf16)
constexpr int NSLOT = 20;     // 0..3 row-dir (2*hf+wc); 4..19 col-dir (4+2*(d-1)+wr)

typedef __attribute__((ext_vector_type(8))) short short8;
typedef __attribute__((ext_vector_type(4))) float f32x4;

#define EXP2(x) __builtin_amdgcn_exp2f(x)

__device__ __forceinline__ unsigned short f2bf(float f) {
  unsigned u = __builtin_bit_cast(unsigned, f);
  u += 0x7FFFu + ((u >> 16) & 1u);
  return (unsigned short)(u >> 16);
}
__device__ __forceinline__ float bf2f(unsigned short h) {
  unsigned u = ((unsigned)h) << 16;
  return __builtin_bit_cast(float, u);
}

__device__ __forceinline__ void stage16(const unsigned short* g, unsigned short* l) {
  __builtin_amdgcn_global_load_lds(
      (const __attribute__((address_space(1))) unsigned int*)g,
      (__attribute__((address_space(3))) unsigned int*)l, 16, 0, 0);
}

// prep: scale by sqrt(log2 e)*mask, bf16-split, swizzled store, row norm^2.
__global__ __launch_bounds__(256) void k_prep(const float* __restrict__ x,
                                              const float* __restrict__ mask,
                                              unsigned short* __restrict__ Y,
                                              float* __restrict__ nsq) {
  const int gid = blockIdx.x * 256 + threadIdx.x;  // one float4 (4 d-elems)
  const int row = gid >> 5;
  const int dq = gid & 31;
  const float4 v = reinterpret_cast<const float4*>(x)[gid];
  const float m = mask[row] * 1.2011224087864498f;  // sqrt(log2 e)
  const float f0 = v.x * m, f1 = v.y * m, f2 = v.z * m, f3 = v.w * m;
  const unsigned short h0 = f2bf(f0), h1 = f2bf(f1), h2 = f2bf(f2), h3 = f2bf(f3);
  const unsigned short e0 = f2bf(f0 - bf2f(h0)), e1 = f2bf(f1 - bf2f(h1)),
                       e2 = f2bf(f2 - bf2f(h2)), e3 = f2bf(f3 - bf2f(h3));
  unsigned short* Yr = Y + (size_t)row * ROWS_US;
  const int sx = dq >> 1, half8 = (dq & 1) * 4;
  const int pos = sx ^ (row & 15);  // XOR within each 16-slot half
  *reinterpret_cast<ushort4*>(Yr + pos * 8 + half8) = make_ushort4(h0, h1, h2, h3);
  *reinterpret_cast<ushort4*>(Yr + (16 + pos) * 8 + half8) = make_ushort4(e0, e1, e2, e3);
  float ss = f0 * f0 + f1 * f1 + f2 * f2 + f3 * f3;
#pragma unroll
  for (int mk = 1; mk < 32; mk <<= 1) ss += __shfl_xor(ss, mk);
  if (dq == 0) nsq[row] = ss;
}

// per-batch max row-norm^2 (16 blocks; NOT fused into k_prep -- R8's
// single-cache-line atomicMax serialized to 375us).
__global__ __launch_bounds__(256) void k_nmax(const float* __restrict__ nsq,
                                              float* __restrict__ nmax) {
  const int b = blockIdx.x;
  const int tid = threadIdx.x;
  float m = 0.f;
  for (int i = tid; i < NL; i += 256) m = fmaxf(m, nsq[b * NL + i]);
#pragma unroll
  for (int mk = 1; mk < 64; mk <<= 1) m = fmaxf(m, __shfl_xor(m, mk));
  __shared__ float red[4];
  if ((tid & 63) == 0) red[tid >> 6] = m;
  __syncthreads();
  if (tid == 0) nmax[b] = fmaxf(fmaxf(red[0], red[1]), fmaxf(red[2], red[3]));
}

// Block decode: xcd = sid&7 owns 2 batches; 32 half-strips per batch.
#define STRIP_DECODE()                                     \
  const int sid = blockIdx.x;                              \
  const int idx = sid >> 3;                                \
  const int b = ((sid & 7) << 1) | (idx >> 5);             \
  const int strip = idx & 31;                              \
  const int ib = strip >> 1, hf = strip & 1;               \
  const int d0 = hf * 4;                                   \
  const int nt = (hf == 0) ? 4 : ((ib < 8) ? 5 : 4);       \
  const int row0 = ib * 128;                               \
  const int tid = threadIdx.x;                             \
  const int lane = tid & 63, wave = tid >> 6;              \
  const int wr = wave >> 1, wc = wave & 1;                 \
  const int lhi = lane >> 4, llo = lane & 15;

// 128x128 tile GEMM, BK=128 x2 chunks (R5's verified body: linear staging so
// LDS inherits Y's per-row XOR swizzle; reads XOR by row&15; 0 bank conflicts).
#define TILE_GEMM(Yb, row0, col0)                                                     \
  f32x4 acc[4][4];                                                                    \
  _Pragma("unroll") for (int rs = 0; rs < 4; ++rs)                                    \
      _Pragma("unroll") for (int cs = 0; cs < 4; ++cs)                                \
          acc[rs][cs] = f32x4{0.f, 0.f, 0.f, 0.f};                                    \
  for (int c = 0; c < 2; ++c) {                                                       \
    __syncthreads();                                                                  \
    _Pragma("unroll") for (int it = 0; it < 8; ++it) {                                \
      const int idx2 = tid + 256 * it;                                                \
      const int r = idx2 >> 4, s = idx2 & 15;                                         \
      stage16(Yb + (size_t)(row0 + r) * ROWS_US + c * 128 + s * 8, At + idx2 * 8);    \
      stage16(Yb + (size_t)(col0 + r) * ROWS_US + c * 128 + s * 8, Bt + idx2 * 8);    \
    }                                                                                 \
    __syncthreads();                                                                  \
    _Pragma("unroll") for (int t4 = 0; t4 < 4; ++t4) {                                \
      const int sl = 4 * t4 + lhi;                                                    \
      short8 af[4], bf[4];                                                            \
      _Pragma("unroll") for (int qq = 0; qq < 4; ++qq) {                              \
        const int ra = 64 * wr + 16 * qq + llo;                                       \
        af[qq] = *(const short8*)(At + ra * 128 + ((sl ^ (ra & 15)) << 3));           \
        const int rb = 64 * wc + 16 * qq + llo;                                       \
        bf[qq] = *(const short8*)(Bt + rb * 128 + ((sl ^ (rb & 15)) << 3));           \
      }                                                                               \
      _Pragma("unroll") for (int rs = 0; rs < 4; ++rs)                                \
          _Pragma("unroll") for (int cs = 0; cs < 4; ++cs)                            \
              acc[rs][cs] = __builtin_amdgcn_mfma_f32_16x16x32_bf16(af[rs], bf[cs],   \
                                                                    acc[rs][cs], 0, 0, 0); \
    }                                                                                 \
  }

// ---- pass 1: csum partials (pure sums; barrier-free per-wave epilogues) ----
__global__ __launch_bounds__(256, 2) void k_esum(const unsigned short* __restrict__ Y,
                                                 const float* __restrict__ nsq,
                                                 const float* __restrict__ nmaxf,
                                                 float* __restrict__ pcs) {
  __shared__ alignas(128) char lds[65536];
  unsigned short* At = (unsigned short*)lds;
  unsigned short* Bt = (unsigned short*)(lds + 32768);
  STRIP_DECODE()
  const unsigned short* Yb = Y + (size_t)b * NL * ROWS_US;
  const float Nmx = nmaxf[b];

  float Cr[16];
#pragma unroll
  for (int rs = 0; rs < 4; ++rs)
#pragma unroll
    for (int rg = 0; rg < 4; ++rg)
      Cr[rs * 4 + rg] = sqrtf(nsq[b * NL + row0 + 64 * wr + 16 * rs + 4 * lhi + rg] * Nmx);

  float racc[16];
#pragma unroll
  for (int i = 0; i < 16; ++i) racc[i] = 0.f;

  for (int dt = 0; dt < nt; ++dt) {
    const int d = d0 + dt;
    const int col0 = ((ib + d) & 15) * 128;
    float Cc[4];
#pragma unroll
    for (int cs = 0; cs < 4; ++cs)
      Cc[cs] = sqrtf(nsq[b * NL + col0 + 64 * wc + 16 * cs + llo] * Nmx);
    TILE_GEMM(Yb, row0, col0)
    // row-direction: csum[row0+i] partial (sum over this tile's cols)
#pragma unroll
    for (int rs = 0; rs < 4; ++rs)
#pragma unroll
      for (int rg = 0; rg < 4; ++rg) {
        float t = 0.f;
#pragma unroll
        for (int cs = 0; cs < 4; ++cs) t += EXP2(acc[rs][cs][rg] - Cr[rs * 4 + rg]);
        racc[rs * 4 + rg] += t;
      }
    // col-direction: per-wave partial straight to global (no LDS, no barrier)
    if (d != 0) {
      float* dst = pcs + ((size_t)(b * NSLOT + 4 + 2 * (d - 1) + wr)) * NL + col0;
#pragma unroll
      for (int cs = 0; cs < 4; ++cs) {
        float u = 0.f;
#pragma unroll
        for (int rs = 0; rs < 4; ++rs)
#pragma unroll
          for (int rg = 0; rg < 4; ++rg) u += EXP2(acc[rs][cs][rg] - Cc[cs]);
        u += __shfl_xor(u, 16);
        u += __shfl_xor(u, 32);
        if (lhi == 0) dst[64 * wc + 16 * cs + llo] = u;
      }
    }
  }
  // strip-end row-direction: llo-reduce, per-(hf,wc) slot, rows disjoint by wr
#pragma unroll
  for (int i = 0; i < 16; ++i) {
    float s = racc[i];
#pragma unroll
    for (int mk = 1; mk < 16; mk <<= 1) s += __shfl_xor(s, mk);
    racc[i] = s;
  }
  if (llo == 0) {
    float* dst = pcs + ((size_t)(b * NSLOT + 2 * hf + wc)) * NL + row0;
#pragma unroll
    for (int rs = 0; rs < 4; ++rs)
#pragma unroll
      for (int rg = 0; rg < 4; ++rg)
        dst[64 * wr + 16 * rs + 4 * lhi + rg] = racc[rs * 4 + rg];
  }
}

// csum partials -> Q = -C - log2(csum)
__global__ __launch_bounds__(256) void k_comb(const float* __restrict__ pcs,
                                              const float* __restrict__ nsq,
                                              const float* __restrict__ nmaxf,
                                              float* __restrict__ Q) {
  const int i = blockIdx.x * 256 + threadIdx.x;  // b*NL + row
  const int b = i >> 11, row = i & (NL - 1);
  const int o = row >> 7;
  float s = 0.f;
#pragma unroll
  for (int c = 0; c < NSLOT; ++c) {
    if (c >= 18 && o < 8) continue;  // d=8 col-dir slots only for owners >= 8
    s += pcs[((size_t)(b * NSLOT + c)) * NL + row];
  }
  Q[i] = -sqrtf(nsq[i] * nmaxf[b]) - __log2f(s);
}

// ---- pass 2: r partials: r[l] = sum_m exp2(S' + Q_m) ----
__global__ __launch_bounds__(256, 2) void k_r(const unsigned short* __restrict__ Y,
                                              const float* __restrict__ Qa,
                                              float* __restrict__ rp) {
  __shared__ alignas(128) char lds[65536];
  unsigned short* At = (unsigned short*)lds;
  unsigned short* Bt = (unsigned short*)(lds + 32768);
  STRIP_DECODE()
  const unsigned short* Yb = Y + (size_t)b * NL * ROWS_US;

  float Qr[16];
#pragma unroll
  for (int rs = 0; rs < 4; ++rs)
#pragma unroll
    for (int rg = 0; rg < 4; ++rg)
      Qr[rs * 4 + rg] = Qa[b * NL + row0 + 64 * wr + 16 * rs + 4 * lhi + rg];

  float racc[16];
#pragma unroll
  for (int i = 0; i < 16; ++i) racc[i] = 0.f;

  for (int dt = 0; dt < nt; ++dt) {
    const int d = d0 + dt;
    const int col0 = ((ib + d) & 15) * 128;
    float Qc[4];
#pragma unroll
    for (int cs = 0; cs < 4; ++cs) Qc[cs] = Qa[b * NL + col0 + 64 * wc + 16 * cs + llo];
    TILE_GEMM(Yb, row0, col0)
    // row-direction: r[row0+i] += sum_m exp2(S' + Q_m) over tile cols
#pragma unroll
    for (int rs = 0; rs < 4; ++rs)
#pragma unroll
      for (int rg = 0; rg < 4; ++rg) {
        float t = 0.f;
#pragma unroll
        for (int cs = 0; cs < 4; ++cs) t += EXP2(acc[rs][cs][rg] + Qc[cs]);
        racc[rs * 4 + rg] += t;
      }
    // col-direction: per-wave partial straight to global
    if (d != 0) {
      float* dst = rp + ((size_t)(b * NSLOT + 4 + 2 * (d - 1) + wr)) * NL + col0;
#pragma unroll
      for (int cs = 0; cs < 4; ++cs) {
        float u = 0.f;
#pragma unroll
        for (int rs = 0; rs < 4; ++rs)
#pragma unroll
          for (int rg = 0; rg < 4; ++rg) u += EXP2(acc[rs][cs][rg] + Qr[rs * 4 + rg]);
        u += __shfl_xor(u, 16);
        u += __shfl_xor(u, 32);
        if (lhi == 0) dst[64 * wc + 16 * cs + llo] = u;
      }
    }
  }
#pragma unroll
  for (int i = 0; i < 16; ++i) {
    float s = racc[i];
#pragma unroll
    for (int mk = 1; mk < 16; mk <<= 1) s += __shfl_xor(s, mk);
    racc[i] = s;
  }
  if (llo == 0) {
    float* dst = rp + ((size_t)(b * NSLOT + 2 * hf + wc)) * NL + row0;
#pragma unroll
    for (int rs = 0; rs < 4; ++rs)
#pragma unroll
      for (int rg = 0; rg < 4; ++rg)
        dst[64 * wr + 16 * rs + 4 * lhi + rg] = racc[rs * 4 + rg];
  }
}

// ---- pass 3a: per-(b,seg) partial of sum_l w[l]*x[l,:] ----
__global__ __launch_bounds__(256) void k_outp(const float* __restrict__ x,
                                              const float* __restrict__ mask,
                                              const float* __restrict__ rp,
                                              float* __restrict__ partial) {
  const int b = blockIdx.y;
  const int seg = blockIdx.x;  // 16 segments of 128 rows; owner block == seg
  const int tid = threadIdx.x;
  const int l0 = seg * 128;
  __shared__ float w_s[128];
  __shared__ float4 red[8][32];
  if (tid < 128) {
    float s = 0.f;
#pragma unroll
    for (int c = 0; c < NSLOT; ++c) {
      if (c >= 18 && seg < 8) continue;
      s += rp[((size_t)(b * NSLOT + c)) * NL + l0 + tid];
    }
    w_s[tid] = s * mask[b * NL + l0 + tid];
  }
  __syncthreads();
  const int dq = tid & 31;
  const int rg = tid >> 5;
  float4 acc = make_float4(0.f, 0.f, 0.f, 0.f);
#pragma unroll 4
  for (int i = 0; i < 16; ++i) {
    const int l = 8 * i + rg;
    const float w = w_s[l];
    const float4 v = *reinterpret_cast<const float4*>(x + ((size_t)b * NL + l0 + l) * ND + 4 * dq);
    acc.x += w * v.x; acc.y += w * v.y; acc.z += w * v.z; acc.w += w * v.w;
  }
  red[rg][dq] = acc;
  __syncthreads();
  if (rg == 0) {
    float4 s = acc;
#pragma unroll
    for (int k = 1; k < 8; ++k) {
      const float4 t = red[k][dq];
      s.x += t.x; s.y += t.y; s.z += t.z; s.w += t.w;
    }
    *reinterpret_cast<float4*>(partial + ((size_t)(b * 16 + seg)) * ND + 4 * dq) = s;
  }
}

// ---- pass 3b: finalize out + constant attn_mean fill ----
__global__ __launch_bounds__(1024) void k_fin(const float* __restrict__ partial,
                                              float* __restrict__ out) {
  const int gid = blockIdx.x * 1024 + threadIdx.x;  // 0..32767
  if (gid < NB * ND) {
    const int b = gid >> 7, d = gid & (ND - 1);
    float s = 0.f;
#pragma unroll
    for (int k = 0; k < 16; ++k) s += partial[(size_t)(b * 16 + k) * ND + d];
    out[gid] = s * (1.0f / NL);
  }
  out[NB * ND + gid] = 1.0f / NL;  // attn_mean == 1/L exactly
}

extern "C" void kernel_launch(void* const* d_in, const int* in_sizes, int n_in,
                              void* d_out, int out_size, void* d_ws, size_t ws_size,
                              hipStream_t stream) {
  const float* x = (const float*)d_in[0];     // [16,2048,128] f32
  const float* mask = (const float*)d_in[1];  // [16,2048] f32
  float* out = (float*)d_out;

  unsigned short* Y = (unsigned short*)d_ws;                   // 16.8 MB
  float* nsq = (float*)(Y + (size_t)NB * NL * ROWS_US);        // [NB*NL]
  float* nmaxf = nsq + NB * NL;                                // [NB]
  float* pcs = nmaxf + 16;                                     // [NB*NSLOT*NL]
  float* rp = pcs;                                             // alias (pcs consumed first)
  float* Q = pcs + (size_t)NB * NSLOT * NL;                    // [NB*NL]
  float* partial = Q + NB * NL;                                // [NB*16*ND]

  k_prep<<<dim3(NB * NL * ND / 4 / 256), 256, 0, stream>>>(x, mask, Y, nsq);
  k_nmax<<<NB, 256, 0, stream>>>(nsq, nmaxf);
  k_esum<<<dim3(512), 256, 0, stream>>>(Y, nsq, nmaxf, pcs);
  k_comb<<<dim3(NB * NL / 256), 256, 0, stream>>>(pcs, nsq, nmaxf, Q);
  k_r<<<dim3(512), 256, 0, stream>>>(Y, Q, rp);
  k_outp<<<dim3(16, NB), 256, 0, stream>>>(x, mask, rp, partial);
  k_fin<<<32, 1024, 0, stream>>>(partial, out);
}

// Round 11
// 67.933 us; speedup vs baseline: 6.7381x; 1.2793x over previous
//
#include <hip/hip_runtime.h>
#include <math.h>

// AttnSum3d via pure-bf16 MFMA + symmetry + bound-shifted softmax.
//   X = x*mask scaled by sqrt(log2 e); H = bf16(X) (L x 128 bf16).
//   S' = H H^T = S*log2(e) + O(2^-8 rounding) (symmetric).
//   R11 insight: the R2-R10 "split" Y=[hi|lo] computed Y Y^T = hi hi^T + lo lo^T
//   (concat along K produces NO cross terms); the lo lo^T part is 2^-18-relative
//   noise. K=128 pure-bf16 is numerically identical (absmax 2.4e-4, 5x under
//   threshold) at HALF the FLOPs/staging.
//   Cauchy-Schwarz bound C_m = n_m*Nmax (norms of the ROUNDED hi rows, so the
//   bound is rigorous for the computed S') >= column max; overshoot <= ~68
//   log2-units -- safe for f32 exp2, no max tracking.
//   csum[m] = sum_l exp2(S'[l,m]-C_m);  Q_m = -C_m - log2(csum_m);
//   r[l] = sum_m exp2(S'[l,m]+Q_m);  out[b,0,d] = (1/L) sum_l X[l,d] r[l];
//   attn_mean = 1/L exactly.
// Strip decomposition (R5): row-block ib owns wrapped distances d=0..7 (+8 if
// ib<8); 512 half-strip blocks, XCD-swizzled (2 batches/XCD). Per strip: At
// staged ONCE + A-fragments hoisted to 64 VGPRs (statically indexed); per tile
// only Bt staged (32 KB, 2 barriers). Barrier-free per-wave epilogues (R10).

constexpr int NB = 16, NL = 2048, ND = 128;
constexpr int ROWS_US = 128;  // ushorts per H row (K = 128 bf16)
constexpr int NSLOT = 20;     // 0..3 row-dir (2*hf+wc); 4..19 col-dir (4+2*(d-1)+wr)

typedef __attribute__((ext_vector_type(8))) short short8;
typedef __attribute__((ext_vector_type(4))) float f32x4;

#define EXP2(x) __builtin_amdgcn_exp2f(x)

__device__ __forceinline__ unsigned short f2bf(float f) {
  unsigned u = __builtin_bit_cast(unsigned, f);
  u += 0x7FFFu + ((u >> 16) & 1u);
  return (unsigned short)(u >> 16);
}
__device__ __forceinline__ float bf2f(unsigned short h) {
  unsigned u = ((unsigned)h) << 16;
  return __builtin_bit_cast(float, u);
}

__device__ __forceinline__ void stage16(const unsigned short* g, unsigned short* l) {
  __builtin_amdgcn_global_load_lds(
      (const __attribute__((address_space(1))) unsigned int*)g,
      (__attribute__((address_space(3))) unsigned int*)l, 16, 0, 0);
}

// prep: scale by sqrt(log2 e)*mask, round to bf16, swizzled store, row norm^2
// of the ROUNDED values (rigorous C-S bound for the computed S').
__global__ __launch_bounds__(256) void k_prep(const float* __restrict__ x,
                                              const float* __restrict__ mask,
                                              unsigned short* __restrict__ Y,
                                              float* __restrict__ nsq) {
  const int gid = blockIdx.x * 256 + threadIdx.x;  // one float4 (4 d-elems)
  const int row = gid >> 5;
  const int dq = gid & 31;
  const float4 v = reinterpret_cast<const float4*>(x)[gid];
  const float m = mask[row] * 1.2011224087864498f;  // sqrt(log2 e)
  const unsigned short h0 = f2bf(v.x * m), h1 = f2bf(v.y * m),
                       h2 = f2bf(v.z * m), h3 = f2bf(v.w * m);
  const float g0 = bf2f(h0), g1 = bf2f(h1), g2 = bf2f(h2), g3 = bf2f(h3);
  unsigned short* Yr = Y + (size_t)row * ROWS_US;
  const int sx = dq >> 1, half8 = (dq & 1) * 4;
  const int pos = sx ^ (row & 15);  // XOR within the 16 16B-slots
  *reinterpret_cast<ushort4*>(Yr + pos * 8 + half8) = make_ushort4(h0, h1, h2, h3);
  float ss = g0 * g0 + g1 * g1 + g2 * g2 + g3 * g3;
#pragma unroll
  for (int mk = 1; mk < 32; mk <<= 1) ss += __shfl_xor(ss, mk);
  if (dq == 0) nsq[row] = ss;
}

// per-batch max row-norm^2 (16 blocks; NOT fused into k_prep -- R8's
// single-cache-line atomicMax serialized to 375us).
__global__ __launch_bounds__(256) void k_nmax(const float* __restrict__ nsq,
                                              float* __restrict__ nmax) {
  const int b = blockIdx.x;
  const int tid = threadIdx.x;
  float m = 0.f;
  for (int i = tid; i < NL; i += 256) m = fmaxf(m, nsq[b * NL + i]);
#pragma unroll
  for (int mk = 1; mk < 64; mk <<= 1) m = fmaxf(m, __shfl_xor(m, mk));
  __shared__ float red[4];
  if ((tid & 63) == 0) red[tid >> 6] = m;
  __syncthreads();
  if (tid == 0) nmax[b] = fmaxf(fmaxf(red[0], red[1]), fmaxf(red[2], red[3]));
}

// Block decode: xcd = sid&7 owns 2 batches; 32 half-strips per batch.
#define STRIP_DECODE()                                     \
  const int sid = blockIdx.x;                              \
  const int idx = sid >> 3;                                \
  const int b = ((sid & 7) << 1) | (idx >> 5);             \
  const int strip = idx & 31;                              \
  const int ib = strip >> 1, hf = strip & 1;               \
  const int d0 = hf * 4;                                   \
  const int nt = (hf == 0) ? 4 : ((ib < 8) ? 5 : 4);       \
  const int row0 = ib * 128;                               \
  const int tid = threadIdx.x;                             \
  const int lane = tid & 63, wave = tid >> 6;              \
  const int wr = wave >> 1, wc = wave & 1;                 \
  const int lhi = lane >> 4, llo = lane & 15;

// Strip prologue: stage At (32 KB, once) and hoist all 16 A-fragments into
// registers (statically indexed -> stays in VGPRs).
#define STRIP_A_PROLOGUE(Yb)                                                   \
  _Pragma("unroll") for (int it = 0; it < 8; ++it) {                           \
    const int idx2 = tid + 256 * it;                                           \
    const int r = idx2 >> 4, s = idx2 & 15;                                    \
    stage16(Yb + (size_t)(row0 + r) * ROWS_US + s * 8, At + idx2 * 8);         \
  }                                                                            \
  __syncthreads();                                                             \
  short8 afr[16];                                                              \
  _Pragma("unroll") for (int t4 = 0; t4 < 4; ++t4) {                           \
    const int sl = 4 * t4 + lhi;                                               \
    _Pragma("unroll") for (int qq = 0; qq < 4; ++qq) {                         \
      const int ra = 64 * wr + 16 * qq + llo;                                  \
      afr[t4 * 4 + qq] = *(const short8*)(At + ra * 128 + ((sl ^ (ra & 15)) << 3)); \
    }                                                                          \
  }

// Per-tile: stage Bt (2 barriers), 64 MFMA. Declares acc[4][4].
#define TILE_GEMM_B(Yb, col0)                                                  \
  f32x4 acc[4][4];                                                             \
  _Pragma("unroll") for (int rs = 0; rs < 4; ++rs)                             \
      _Pragma("unroll") for (int cs = 0; cs < 4; ++cs)                         \
          acc[rs][cs] = f32x4{0.f, 0.f, 0.f, 0.f};                             \
  __syncthreads(); /* all waves done reading prev Bt */                        \
  _Pragma("unroll") for (int it = 0; it < 8; ++it) {                           \
    const int idx2 = tid + 256 * it;                                           \
    const int r = idx2 >> 4, s = idx2 & 15;                                    \
    stage16(Yb + (size_t)(col0 + r) * ROWS_US + s * 8, Bt + idx2 * 8);         \
  }                                                                            \
  __syncthreads(); /* Bt (and At on first tile) ready */                       \
  _Pragma("unroll") for (int t4 = 0; t4 < 4; ++t4) {                           \
    const int sl = 4 * t4 + lhi;                                               \
    short8 bfx[4];                                                             \
    _Pragma("unroll") for (int qq = 0; qq < 4; ++qq) {                         \
      const int rb = 64 * wc + 16 * qq + llo;                                  \
      bfx[qq] = *(const short8*)(Bt + rb * 128 + ((sl ^ (rb & 15)) << 3));     \
    }                                                                          \
    _Pragma("unroll") for (int rs = 0; rs < 4; ++rs)                           \
        _Pragma("unroll") for (int cs = 0; cs < 4; ++cs)                       \
            acc[rs][cs] = __builtin_amdgcn_mfma_f32_16x16x32_bf16(             \
                afr[t4 * 4 + rs], bfx[cs], acc[rs][cs], 0, 0, 0);              \
  }

// ---- pass 1: csum partials (pure sums; barrier-free per-wave epilogues) ----
__global__ __launch_bounds__(256, 2) void k_esum(const unsigned short* __restrict__ Y,
                                                 const float* __restrict__ nsq,
                                                 const float* __restrict__ nmaxf,
                                                 float* __restrict__ pcs) {
  __shared__ alignas(128) char lds[65536];
  unsigned short* At = (unsigned short*)lds;
  unsigned short* Bt = (unsigned short*)(lds + 32768);
  STRIP_DECODE()
  const unsigned short* Yb = Y + (size_t)b * NL * ROWS_US;
  const float Nmx = nmaxf[b];

  float Cr[16];
#pragma unroll
  for (int rs = 0; rs < 4; ++rs)
#pragma unroll
    for (int rg = 0; rg < 4; ++rg)
      Cr[rs * 4 + rg] = sqrtf(nsq[b * NL + row0 + 64 * wr + 16 * rs + 4 * lhi + rg] * Nmx);

  STRIP_A_PROLOGUE(Yb)

  float racc[16];
#pragma unroll
  for (int i = 0; i < 16; ++i) racc[i] = 0.f;

  for (int dt = 0; dt < nt; ++dt) {
    const int d = d0 + dt;
    const int col0 = ((ib + d) & 15) * 128;
    float Cc[4];
#pragma unroll
    for (int cs = 0; cs < 4; ++cs)
      Cc[cs] = sqrtf(nsq[b * NL + col0 + 64 * wc + 16 * cs + llo] * Nmx);
    TILE_GEMM_B(Yb, col0)
    // row-direction: csum[row0+i] partial (sum over this tile's cols)
#pragma unroll
    for (int rs = 0; rs < 4; ++rs)
#pragma unroll
      for (int rg = 0; rg < 4; ++rg) {
        float t = 0.f;
#pragma unroll
        for (int cs = 0; cs < 4; ++cs) t += EXP2(acc[rs][cs][rg] - Cr[rs * 4 + rg]);
        racc[rs * 4 + rg] += t;
      }
    // col-direction: per-wave partial straight to global (no LDS, no barrier)
    if (d != 0) {
      float* dst = pcs + ((size_t)(b * NSLOT + 4 + 2 * (d - 1) + wr)) * NL + col0;
#pragma unroll
      for (int cs = 0; cs < 4; ++cs) {
        float u = 0.f;
#pragma unroll
        for (int rs = 0; rs < 4; ++rs)
#pragma unroll
          for (int rg = 0; rg < 4; ++rg) u += EXP2(acc[rs][cs][rg] - Cc[cs]);
        u += __shfl_xor(u, 16);
        u += __shfl_xor(u, 32);
        if (lhi == 0) dst[64 * wc + 16 * cs + llo] = u;
      }
    }
  }
  // strip-end row-direction: llo-reduce, per-(hf,wc) slot, rows disjoint by wr
#pragma unroll
  for (int i = 0; i < 16; ++i) {
    float s = racc[i];
#pragma unroll
    for (int mk = 1; mk < 16; mk <<= 1) s += __shfl_xor(s, mk);
    racc[i] = s;
  }
  if (llo == 0) {
    float* dst = pcs + ((size_t)(b * NSLOT + 2 * hf + wc)) * NL + row0;
#pragma unroll
    for (int rs = 0; rs < 4; ++rs)
#pragma unroll
      for (int rg = 0; rg < 4; ++rg)
        dst[64 * wr + 16 * rs + 4 * lhi + rg] = racc[rs * 4 + rg];
  }
}

// csum partials -> Q = -C - log2(csum)
__global__ __launch_bounds__(256) void k_comb(const float* __restrict__ pcs,
                                              const float* __restrict__ nsq,
                                              const float* __restrict__ nmaxf,
                                              float* __restrict__ Q) {
  const int i = blockIdx.x * 256 + threadIdx.x;  // b*NL + row
  const int b = i >> 11, row = i & (NL - 1);
  const int o = row >> 7;
  float s = 0.f;
#pragma unroll
  for (int c = 0; c < NSLOT; ++c) {
    if (c >= 18 && o < 8) continue;  // d=8 col-dir slots only for owners >= 8
    s += pcs[((size_t)(b * NSLOT + c)) * NL + row];
  }
  Q[i] = -sqrtf(nsq[i] * nmaxf[b]) - __log2f(s);
}

// ---- pass 2: r partials: r[l] = sum_m exp2(S' + Q_m) ----
__global__ __launch_bounds__(256, 2) void k_r(const unsigned short* __restrict__ Y,
                                              const float* __restrict__ Qa,
                                              float* __restrict__ rp) {
  __shared__ alignas(128) char lds[65536];
  unsigned short* At = (unsigned short*)lds;
  unsigned short* Bt = (unsigned short*)(lds + 32768);
  STRIP_DECODE()
  const unsigned short* Yb = Y + (size_t)b * NL * ROWS_US;

  float Qr[16];
#pragma unroll
  for (int rs = 0; rs < 4; ++rs)
#pragma unroll
    for (int rg = 0; rg < 4; ++rg)
      Qr[rs * 4 + rg] = Qa[b * NL + row0 + 64 * wr + 16 * rs + 4 * lhi + rg];

  STRIP_A_PROLOGUE(Yb)

  float racc[16];
#pragma unroll
  for (int i = 0; i < 16; ++i) racc[i] = 0.f;

  for (int dt = 0; dt < nt; ++dt) {
    const int d = d0 + dt;
    const int col0 = ((ib + d) & 15) * 128;
    float Qc[4];
#pragma unroll
    for (int cs = 0; cs < 4; ++cs) Qc[cs] = Qa[b * NL + col0 + 64 * wc + 16 * cs + llo];
    TILE_GEMM_B(Yb, col0)
    // row-direction: r[row0+i] += sum_m exp2(S' + Q_m) over tile cols
#pragma unroll
    for (int rs = 0; rs < 4; ++rs)
#pragma unroll
      for (int rg = 0; rg < 4; ++rg) {
        float t = 0.f;
#pragma unroll
        for (int cs = 0; cs < 4; ++cs) t += EXP2(acc[rs][cs][rg] + Qc[cs]);
        racc[rs * 4 + rg] += t;
      }
    // col-direction: per-wave partial straight to global
    if (d != 0) {
      float* dst = rp + ((size_t)(b * NSLOT + 4 + 2 * (d - 1) + wr)) * NL + col0;
#pragma unroll
      for (int cs = 0; cs < 4; ++cs) {
        float u = 0.f;
#pragma unroll
        for (int rs = 0; rs < 4; ++rs)
#pragma unroll
          for (int rg = 0; rg < 4; ++rg) u += EXP2(acc[rs][cs][rg] + Qr[rs * 4 + rg]);
        u += __shfl_xor(u, 16);
        u += __shfl_xor(u, 32);
        if (lhi == 0) dst[64 * wc + 16 * cs + llo] = u;
      }
    }
  }
#pragma unroll
  for (int i = 0; i < 16; ++i) {
    float s = racc[i];
#pragma unroll
    for (int mk = 1; mk < 16; mk <<= 1) s += __shfl_xor(s, mk);
    racc[i] = s;
  }
  if (llo == 0) {
    float* dst = rp + ((size_t)(b * NSLOT + 2 * hf + wc)) * NL + row0;
#pragma unroll
    for (int rs = 0; rs < 4; ++rs)
#pragma unroll
      for (int rg = 0; rg < 4; ++rg)
        dst[64 * wr + 16 * rs + 4 * lhi + rg] = racc[rs * 4 + rg];
  }
}

// ---- pass 3a: per-(b,seg) partial of sum_l w[l]*x[l,:] ----
__global__ __launch_bounds__(256) void k_outp(const float* __restrict__ x,
                                              const float* __restrict__ mask,
                                              const float* __restrict__ rp,
                                              float* __restrict__ partial) {
  const int b = blockIdx.y;
  const int seg = blockIdx.x;  // 16 segments of 128 rows; owner block == seg
  const int tid = threadIdx.x;
  const int l0 = seg * 128;
  __shared__ float w_s[128];
  __shared__ float4 red[8][32];
  if (tid < 128) {
    float s = 0.f;
#pragma unroll
    for (int c = 0; c < NSLOT; ++c) {
      if (c >= 18 && seg < 8) continue;
      s += rp[((size_t)(b * NSLOT + c)) * NL + l0 + tid];
    }
    w_s[tid] = s * mask[b * NL + l0 + tid];
  }
  __syncthreads();
  const int dq = tid & 31;
  const int rg = tid >> 5;
  float4 acc = make_float4(0.f, 0.f, 0.f, 0.f);
#pragma unroll 4
  for (int i = 0; i < 16; ++i) {
    const int l = 8 * i + rg;
    const float w = w_s[l];
    const float4 v = *reinterpret_cast<const float4*>(x + ((size_t)b * NL + l0 + l) * ND + 4 * dq);
    acc.x += w * v.x; acc.y += w * v.y; acc.z += w * v.z; acc.w += w * v.w;
  }
  red[rg][dq] = acc;
  __syncthreads();
  if (rg == 0) {
    float4 s = acc;
#pragma unroll
    for (int k = 1; k < 8; ++k) {
      const float4 t = red[k][dq];
      s.x += t.x; s.y += t.y; s.z += t.z; s.w += t.w;
    }
    *reinterpret_cast<float4*>(partial + ((size_t)(b * 16 + seg)) * ND + 4 * dq) = s;
  }
}

// ---- pass 3b: finalize out + constant attn_mean fill ----
__global__ __launch_bounds__(1024) void k_fin(const float* __restrict__ partial,
                                              float* __restrict__ out) {
  const int gid = blockIdx.x * 1024 + threadIdx.x;  // 0..32767
  if (gid < NB * ND) {
    const int b = gid >> 7, d = gid & (ND - 1);
    float s = 0.f;
#pragma unroll
    for (int k = 0; k < 16; ++k) s += partial[(size_t)(b * 16 + k) * ND + d];
    out[gid] = s * (1.0f / NL);
  }
  out[NB * ND + gid] = 1.0f / NL;  // attn_mean == 1/L exactly
}

extern "C" void kernel_launch(void* const* d_in, const int* in_sizes, int n_in,
                              void* d_out, int out_size, void* d_ws, size_t ws_size,
                              hipStream_t stream) {
  const float* x = (const float*)d_in[0];     // [16,2048,128] f32
  const float* mask = (const float*)d_in[1];  // [16,2048] f32
  float* out = (float*)d_out;

  unsigned short* Y = (unsigned short*)d_ws;                   // 8.4 MB
  float* nsq = (float*)(Y + (size_t)NB * NL * ROWS_US);        // [NB*NL]
  float* nmaxf = nsq + NB * NL;                                // [NB]
  float* pcs = nmaxf + 16;                                     // [NB*NSLOT*NL]
  float* rp = pcs;                                             // alias (pcs consumed first)
  float* Q = pcs + (size_t)NB * NSLOT * NL;                    // [NB*NL]
  float* partial = Q + NB * NL;                                // [NB*16*ND]

  k_prep<<<dim3(NB * NL * ND / 4 / 256), 256, 0, stream>>>(x, mask, Y, nsq);
  k_nmax<<<NB, 256, 0, stream>>>(nsq, nmaxf);
  k_esum<<<dim3(512), 256, 0, stream>>>(Y, nsq, nmaxf, pcs);
  k_comb<<<dim3(NB * NL / 256), 256, 0, stream>>>(pcs, nsq, nmaxf, Q);
  k_r<<<dim3(512), 256, 0, stream>>>(Y, Q, rp);
  k_outp<<<dim3(16, NB), 256, 0, stream>>>(x, mask, rp, partial);
  k_fin<<<32, 1024, 0, stream>>>(partial, out);
}